// Round 12
// baseline (1941.922 us; speedup 1.0000x reference)
//
#include <hip/hip_runtime.h>
#include <hip/hip_bf16.h>
#include <stdint.h>

#define NN 100000
#define NE 1600000
#define EDGE_GRID 448      // leave ~64 co-residency slots for updA side channel
#define UPDA_BLOCKS 391    // ceil(NN/256)

typedef __attribute__((ext_vector_type(4))) float f32x4;
typedef __attribute__((ext_vector_type(8))) __bf16 bf16x8;
typedef __attribute__((ext_vector_type(8))) short s16x8;
typedef __attribute__((ext_vector_type(4))) unsigned int u32x4;

__device__ __forceinline__ unsigned short f2bf(float f) {
  unsigned int u = __builtin_bit_cast(unsigned int, f);
  u += 0x7fffu + ((u >> 16) & 1u);
  return (unsigned short)(u >> 16);
}

__device__ __forceinline__ f32x4 mfma16(bf16x8 a, bf16x8 b, f32x4 c) {
  return __builtin_amdgcn_mfma_f32_16x16x32_bf16(a, b, c, 0, 0, 0);
}

// ---------------------------------------------------------------------------
// setup: msg weights + global -> bf16
// ---------------------------------------------------------------------------
__global__ void convert_kernel(const float* __restrict__ w1, const float* __restrict__ w2,
                               const float* __restrict__ g,
                               unsigned short* __restrict__ w1b, unsigned short* __restrict__ w2b,
                               unsigned short* __restrict__ gb)
{
  const int tid = blockIdx.x * 256 + threadIdx.x;
  if (tid < 256 * 128) w1b[tid] = f2bf(w1[tid]);
  if (tid < 128 * 128) w2b[tid] = f2bf(w2[tid]);
  if (tid < 64) gb[tid] = f2bf(g[tid]);
}

// ---------------------------------------------------------------------------
// fused kernel, heterogeneous by blockIdx:
//  blocks [0, EDGE_GRID): r3 edge kernel verbatim -- msg-MLP via bf16 MFMA,
//    direct f32 atomic scatter into agg + deg. Atomic-bound (r9/r10), so
//    448 vs 512 blocks should be ~neutral.
//  blocks [EDGE_GRID, ...): updA -- agg-independent half of upd1
//    (b1 + node@U1[0:128] + gs@U1[256:320]). These drain through the ~64
//    free co-residency slots WHILE edge runs (true overlap this time).
// ---------------------------------------------------------------------------
__global__ __launch_bounds__(256, 2) void fused_kernel(
    const int* __restrict__ ei,
    const float* __restrict__ edge_state,
    const float* __restrict__ node_state,
    const unsigned short* __restrict__ w1b,
    const unsigned short* __restrict__ w2b,
    const float* __restrict__ bias1g,
    const float* __restrict__ bias2g,
    const unsigned short* __restrict__ gb,
    float* __restrict__ agg,
    float* __restrict__ deg,
    const float* __restrict__ u1,     // f32 [320][128]
    const float* __restrict__ ub1,
    const float* __restrict__ gs,     // f32 [64]
    float* __restrict__ hpart)
{
  __shared__ unsigned short sX[64 * 256];  // 32 KB
  __shared__ unsigned short sH[64 * 128];  // 16 KB
  __shared__ int sDst[64];

  const int t = threadIdx.x;

  if (blockIdx.x >= EDGE_GRID) {
    // ================= updA: agg-independent half of upd1 =================
    const int n = (blockIdx.x - EDGE_GRID) * 256 + t;
    const bool act = n < NN;
    const size_t row = (size_t)(act ? n : 0) * 128;

    f32x4 acc[32];
#pragma unroll
    for (int c = 0; c < 32; ++c) acc[c] = *(const f32x4*)(ub1 + 4 * c);

    for (int k4 = 0; k4 < 32; ++k4) {          // node part: k = 0..127
      const f32x4 x = *(const f32x4*)(node_state + row + 4 * k4);
#pragma unroll
      for (int kk = 0; kk < 4; ++kk) {
        const float xk = x[kk];
        const float* wr = u1 + (size_t)(4 * k4 + kk) * 128;
#pragma unroll
        for (int c = 0; c < 32; ++c) acc[c] += xk * *(const f32x4*)(wr + 4 * c);
      }
    }
    for (int k = 0; k < 64; ++k) {             // global part: k = 256..319
      const float xk = gs[k];
      const float* wr = u1 + (size_t)(256 + k) * 128;
#pragma unroll
      for (int c = 0; c < 32; ++c) acc[c] += xk * *(const f32x4*)(wr + 4 * c);
    }
    if (act) {
      float* o = hpart + (size_t)n * 128;
#pragma unroll
      for (int c = 0; c < 32; ++c) *(f32x4*)(o + 4 * c) = acc[c];
    }
    return;
  }

  // ======================= edge path (r3 verbatim) ========================
  const int lane = t & 63;
  const int wv = t >> 6;
  const int l15 = lane & 15;
  const int lq = lane >> 4;

  bf16x8 b1f[8][2], b2f[4][2];
  float bs1[2], bs2[2];
  for (int n = 0; n < 2; ++n) {
    const int col = wv * 32 + n * 16 + l15;
    bs1[n] = bias1g[col];
    bs2[n] = bias2g[col];
    for (int ks = 0; ks < 8; ++ks) {
      const int k0 = ks * 32 + lq * 8;
      s16x8 v;
#pragma unroll
      for (int j = 0; j < 8; ++j) v[j] = (short)w1b[(k0 + j) * 128 + col];
      b1f[ks][n] = __builtin_bit_cast(bf16x8, v);
    }
    for (int ks = 0; ks < 4; ++ks) {
      const int k0 = ks * 32 + lq * 8;
      s16x8 v;
#pragma unroll
      for (int j = 0; j < 8; ++j) v[j] = (short)w2b[(k0 + j) * 128 + col];
      b2f[ks][n] = __builtin_bit_cast(bf16x8, v);
    }
  }

  const int r = t >> 2;
  const int p = t & 3;
  const int rs = r & 7;

  for (int tile = blockIdx.x; tile < NE / 64; tile += EDGE_GRID) {
    __syncthreads();
    const int e0 = tile * 64;

    const int src = ei[e0 + r];
    if (p == 0) {
      const int d = ei[NE + e0 + r];
      sDst[r] = d;
      atomicAdd(&deg[d], 1.0f);
    }
    {  // node gather (f32 -> bf16): chunks 0..15
      const f32x4* nsv = (const f32x4*)(node_state + (size_t)src * 128 + p * 32);
#pragma unroll
      for (int j = 0; j < 4; ++j) {
        f32x4 x0 = nsv[2 * j], x1 = nsv[2 * j + 1];
        unsigned short buf[8];
#pragma unroll
        for (int i = 0; i < 4; ++i) { buf[i] = f2bf(x0[i]); buf[4 + i] = f2bf(x1[i]); }
        const int c = p * 4 + j;
        *(u32x4*)((char*)sX + r * 512 + ((c ^ rs) * 16)) = *(u32x4*)buf;
      }
    }
    {  // edge_state: f32 -> bf16, chunks 16..23
      const f32x4* es = (const f32x4*)(edge_state + (size_t)e0 * 64 + r * 64 + p * 16);
      f32x4 e0v = es[0], e1v = es[1], e2v = es[2], e3v = es[3];
      unsigned short bufa[8], bufb[8];
#pragma unroll
      for (int i = 0; i < 4; ++i) {
        bufa[i] = f2bf(e0v[i]); bufa[4 + i] = f2bf(e1v[i]);
        bufb[i] = f2bf(e2v[i]); bufb[4 + i] = f2bf(e3v[i]);
      }
      const int c = 16 + 2 * p;
      *(u32x4*)((char*)sX + r * 512 + ((c ^ rs) * 16)) = *(u32x4*)bufa;
      *(u32x4*)((char*)sX + r * 512 + (((c + 1) ^ rs) * 16)) = *(u32x4*)bufb;
    }
    {  // global (pre-converted bf16): chunks 24..31
      const u32x4* g = (const u32x4*)(gb + p * 16);
      const int c = 24 + 2 * p;
      *(u32x4*)((char*)sX + r * 512 + ((c ^ rs) * 16)) = g[0];
      *(u32x4*)((char*)sX + r * 512 + (((c + 1) ^ rs) * 16)) = g[1];
    }
    __syncthreads();

    // phase 1
    f32x4 acc[4][2];
#pragma unroll
    for (int m = 0; m < 4; ++m)
#pragma unroll
      for (int n = 0; n < 2; ++n)
        acc[m][n] = (f32x4){bs1[n], bs1[n], bs1[n], bs1[n]};
#pragma unroll
    for (int ks = 0; ks < 8; ++ks) {
      bf16x8 a[4];
#pragma unroll
      for (int m = 0; m < 4; ++m) {
        const int row = m * 16 + l15;
        a[m] = *(const bf16x8*)((const char*)sX + row * 512 + (((4 * ks + lq) ^ (row & 7)) * 16));
      }
#pragma unroll
      for (int m = 0; m < 4; ++m)
#pragma unroll
        for (int n = 0; n < 2; ++n)
          acc[m][n] = mfma16(a[m], b1f[ks][n], acc[m][n]);
    }
#pragma unroll
    for (int m = 0; m < 4; ++m)
#pragma unroll
      for (int n = 0; n < 2; ++n)
#pragma unroll
        for (int i = 0; i < 4; ++i) {
          const int row = m * 16 + lq * 4 + i;
          const int col = wv * 32 + n * 16 + l15;
          float v = acc[m][n][i];
          v = v > 0.f ? v : 0.f;
          *(unsigned short*)((char*)sH + row * 256 +
                             ((((col >> 3) ^ (row & 7)) * 16) + (col & 7) * 2)) = f2bf(v);
        }
    __syncthreads();

    // phase 2 + scatter
    f32x4 acc2[4][2];
#pragma unroll
    for (int m = 0; m < 4; ++m)
#pragma unroll
      for (int n = 0; n < 2; ++n)
        acc2[m][n] = (f32x4){bs2[n], bs2[n], bs2[n], bs2[n]};
#pragma unroll
    for (int ks = 0; ks < 4; ++ks) {
      bf16x8 a[4];
#pragma unroll
      for (int m = 0; m < 4; ++m) {
        const int row = m * 16 + l15;
        a[m] = *(const bf16x8*)((const char*)sH + row * 256 + (((4 * ks + lq) ^ (row & 7)) * 16));
      }
#pragma unroll
      for (int m = 0; m < 4; ++m)
#pragma unroll
        for (int n = 0; n < 2; ++n)
          acc2[m][n] = mfma16(a[m], b2f[ks][n], acc2[m][n]);
    }
#pragma unroll
    for (int m = 0; m < 4; ++m)
#pragma unroll
      for (int i = 0; i < 4; ++i) {
        const int row = m * 16 + lq * 4 + i;
        const int d = sDst[row];
#pragma unroll
        for (int n = 0; n < 2; ++n) {
          const int col = wv * 32 + n * 16 + l15;
          atomicAdd(&agg[(size_t)d * 128 + col], acc2[m][n][i]);
        }
      }
  }
}

// ---------------------------------------------------------------------------
// updBC: fused updB + upd2, h1 held in registers (bitwise-identical f32 math)
//   h1 = relu(hpart + (agg/deg) @ U1[128:256])
//   delta = h1 @ U2 + b2; x = node + delta; out = LN(x)*gamma + beta
// __launch_bounds__(128) with no min-wave bound -> allocator free up to 512
// VGPR, no spill (acc 128 + acc2 128 + temps). All acc indexing static.
// ---------------------------------------------------------------------------
__global__ __launch_bounds__(128) void updBC_kernel(
    const float* __restrict__ node_state,
    const float* __restrict__ hpart,
    const float* __restrict__ agg,
    const float* __restrict__ deg,
    const float* __restrict__ u1,    // [320][128] f32
    const float* __restrict__ u2,    // [128][128] f32
    const float* __restrict__ b2,
    const float* __restrict__ lng,
    const float* __restrict__ lnb,
    float* __restrict__ out)
{
  const int n = blockIdx.x * 128 + threadIdx.x;
  const bool act = n < NN;
  const size_t row = (size_t)(act ? n : 0) * 128;

  // ---- h1 = relu(hpart + (agg/deg) @ U1[128:256]) ----
  f32x4 acc[32];
#pragma unroll
  for (int c = 0; c < 32; ++c) acc[c] = *(const f32x4*)(hpart + row + 4 * c);

  const float rdeg = act ? (1.0f / fmaxf(deg[n], 1.0f)) : 0.0f;

  for (int k4 = 0; k4 < 32; ++k4) {
    const f32x4 x = *(const f32x4*)(agg + row + 4 * k4);
#pragma unroll
    for (int kk = 0; kk < 4; ++kk) {
      const float xk = x[kk] * rdeg;
      const float* wr = u1 + (size_t)(128 + 4 * k4 + kk) * 128;
#pragma unroll
      for (int c = 0; c < 32; ++c) acc[c] += xk * *(const f32x4*)(wr + 4 * c);
    }
  }
#pragma unroll
  for (int c = 0; c < 32; ++c) {
#pragma unroll
    for (int i = 0; i < 4; ++i) acc[c][i] = acc[c][i] > 0.f ? acc[c][i] : 0.f;
  }

  // ---- delta = h1 @ U2 + b2 (h1 in registers; k-loop fully unrolled) ----
  f32x4 acc2[32];
#pragma unroll
  for (int c = 0; c < 32; ++c) acc2[c] = *(const f32x4*)(b2 + 4 * c);

#pragma unroll
  for (int k4 = 0; k4 < 32; ++k4) {
    const f32x4 h = acc[k4];               // static index
#pragma unroll
    for (int kk = 0; kk < 4; ++kk) {
      const float hk = h[kk];
      const float* wr = u2 + (size_t)(4 * k4 + kk) * 128;
#pragma unroll
      for (int c = 0; c < 32; ++c) acc2[c] += hk * *(const f32x4*)(wr + 4 * c);
    }
  }

  // ---- x = node + delta; LayerNorm ----
  if (act) {
    float s = 0.f, s2 = 0.f;
#pragma unroll
    for (int c = 0; c < 32; ++c) {
      const f32x4 nd = *(const f32x4*)(node_state + row + 4 * c);
      f32x4 x = nd + acc2[c];
      acc2[c] = x;
#pragma unroll
      for (int i = 0; i < 4; ++i) { s += x[i]; s2 += x[i] * x[i]; }
    }
    const float mu = s * (1.0f / 128.0f);
    float var = s2 * (1.0f / 128.0f) - mu * mu;
    var = var < 0.f ? 0.f : var;
    const float rstd = rsqrtf(var + 1e-5f);
    float* o = out + (size_t)n * 128;
#pragma unroll
    for (int c = 0; c < 32; ++c) {
      const f32x4 g = *(const f32x4*)(lng + 4 * c);
      const f32x4 b = *(const f32x4*)(lnb + 4 * c);
      f32x4 x = acc2[c];
#pragma unroll
      for (int i = 0; i < 4; ++i) x[i] = (x[i] - mu) * rstd * g[i] + b[i];
      *(f32x4*)(o + 4 * c) = x;
    }
  }
}

// ---------------------------------------------------------------------------
extern "C" void kernel_launch(void* const* d_in, const int* in_sizes, int n_in,
                              void* d_out, int out_size, void* d_ws, size_t ws_size,
                              hipStream_t stream)
{
  const float* node_state = (const float*)d_in[0];
  const int* ei           = (const int*)d_in[1];   // int64 in reference -> int32 from harness
  const float* edge_state = (const float*)d_in[2];
  const float* gstate     = (const float*)d_in[3];
  const float* msg_w1     = (const float*)d_in[4];
  const float* msg_b1     = (const float*)d_in[5];
  const float* msg_w2     = (const float*)d_in[6];
  const float* msg_b2     = (const float*)d_in[7];
  const float* upd_w1     = (const float*)d_in[8];
  const float* upd_b1     = (const float*)d_in[9];
  const float* upd_w2     = (const float*)d_in[10];
  const float* upd_b2     = (const float*)d_in[11];
  const float* ln_g       = (const float*)d_in[12];
  const float* ln_b       = (const float*)d_in[13];

  char* ws = (char*)d_ws;
  float* agg              = (float*)(ws + 0);                  //  51,200,000
  float* deg              = (float*)(ws + 51200000);           //     400,000
  float* hpart            = (float*)(ws + 51600000);           //  51,200,000
  unsigned short* w1b     = (unsigned short*)(ws + 102800000); //      65,536
  unsigned short* w2b     = (unsigned short*)(ws + 102865536); //      32,768
  unsigned short* gb      = (unsigned short*)(ws + 102898304); //         128
  (void)ws_size; (void)in_sizes; (void)n_in; (void)out_size;

  hipMemsetAsync(ws, 0, 51600000, stream);  // agg + deg
  hipLaunchKernelGGL(convert_kernel, dim3(160), dim3(256), 0, stream,
                     msg_w1, msg_w2, gstate, w1b, w2b, gb);
  hipLaunchKernelGGL(fused_kernel, dim3(EDGE_GRID + UPDA_BLOCKS), dim3(256), 0, stream,
                     ei, edge_state, node_state, w1b, w2b, msg_b1, msg_b2, gb,
                     agg, deg, upd_w1, upd_b1, gstate, hpart);
  hipLaunchKernelGGL(updBC_kernel, dim3((NN + 127) / 128), dim3(128), 0, stream,
                     node_state, hpart, agg, deg, upd_w1, upd_w2, upd_b2,
                     ln_g, ln_b, (float*)d_out);
}

// Round 13
// 1054.350 us; speedup vs baseline: 1.8418x; 1.8418x over previous
//
#include <hip/hip_runtime.h>
#include <hip/hip_bf16.h>
#include <stdint.h>

#define NN 100000
#define NE 1600000
#define EDGE_GRID 448      // r12-proven: overlap real at 448 (fused ~790 us)
#define UPDA_BLOCKS 391    // ceil(NN/256)

typedef __attribute__((ext_vector_type(4))) float f32x4;
typedef __attribute__((ext_vector_type(8))) __bf16 bf16x8;
typedef __attribute__((ext_vector_type(8))) short s16x8;
typedef __attribute__((ext_vector_type(4))) unsigned int u32x4;

__device__ __forceinline__ unsigned short f2bf(float f) {
  unsigned int u = __builtin_bit_cast(unsigned int, f);
  u += 0x7fffu + ((u >> 16) & 1u);
  return (unsigned short)(u >> 16);
}

__device__ __forceinline__ f32x4 mfma16(bf16x8 a, bf16x8 b, f32x4 c) {
  return __builtin_amdgcn_mfma_f32_16x16x32_bf16(a, b, c, 0, 0, 0);
}

// ---------------------------------------------------------------------------
// setup: msg weights + global -> bf16
// ---------------------------------------------------------------------------
__global__ void convert_kernel(const float* __restrict__ w1, const float* __restrict__ w2,
                               const float* __restrict__ g,
                               unsigned short* __restrict__ w1b, unsigned short* __restrict__ w2b,
                               unsigned short* __restrict__ gb)
{
  const int tid = blockIdx.x * 256 + threadIdx.x;
  if (tid < 256 * 128) w1b[tid] = f2bf(w1[tid]);
  if (tid < 128 * 128) w2b[tid] = f2bf(w2[tid]);
  if (tid < 64) gb[tid] = f2bf(g[tid]);
}

// ---------------------------------------------------------------------------
// fused kernel (r12 verbatim -- overlap proven at EDGE_GRID=448):
//  blocks [0, EDGE_GRID): r3 edge kernel -- msg-MLP via bf16 MFMA,
//    direct f32 atomic scatter into agg + deg (atomic-bound).
//  blocks [EDGE_GRID, ...): updA -- agg-independent half of upd1, drains
//    through free co-residency slots while edge runs.
// ---------------------------------------------------------------------------
__global__ __launch_bounds__(256, 2) void fused_kernel(
    const int* __restrict__ ei,
    const float* __restrict__ edge_state,
    const float* __restrict__ node_state,
    const unsigned short* __restrict__ w1b,
    const unsigned short* __restrict__ w2b,
    const float* __restrict__ bias1g,
    const float* __restrict__ bias2g,
    const unsigned short* __restrict__ gb,
    float* __restrict__ agg,
    float* __restrict__ deg,
    const float* __restrict__ u1,     // f32 [320][128]
    const float* __restrict__ ub1,
    const float* __restrict__ gs,     // f32 [64]
    float* __restrict__ hpart)
{
  __shared__ unsigned short sX[64 * 256];  // 32 KB
  __shared__ unsigned short sH[64 * 128];  // 16 KB
  __shared__ int sDst[64];

  const int t = threadIdx.x;

  if (blockIdx.x >= EDGE_GRID) {
    // ================= updA: agg-independent half of upd1 =================
    const int n = (blockIdx.x - EDGE_GRID) * 256 + t;
    const bool act = n < NN;
    const size_t row = (size_t)(act ? n : 0) * 128;

    f32x4 acc[32];
#pragma unroll
    for (int c = 0; c < 32; ++c) acc[c] = *(const f32x4*)(ub1 + 4 * c);

    for (int k4 = 0; k4 < 32; ++k4) {          // node part: k = 0..127
      const f32x4 x = *(const f32x4*)(node_state + row + 4 * k4);
#pragma unroll
      for (int kk = 0; kk < 4; ++kk) {
        const float xk = x[kk];
        const float* wr = u1 + (size_t)(4 * k4 + kk) * 128;
#pragma unroll
        for (int c = 0; c < 32; ++c) acc[c] += xk * *(const f32x4*)(wr + 4 * c);
      }
    }
    for (int k = 0; k < 64; ++k) {             // global part: k = 256..319
      const float xk = gs[k];
      const float* wr = u1 + (size_t)(256 + k) * 128;
#pragma unroll
      for (int c = 0; c < 32; ++c) acc[c] += xk * *(const f32x4*)(wr + 4 * c);
    }
    if (act) {
      float* o = hpart + (size_t)n * 128;
#pragma unroll
      for (int c = 0; c < 32; ++c) *(f32x4*)(o + 4 * c) = acc[c];
    }
    return;
  }

  // ======================= edge path (r3 verbatim) ========================
  const int lane = t & 63;
  const int wv = t >> 6;
  const int l15 = lane & 15;
  const int lq = lane >> 4;

  bf16x8 b1f[8][2], b2f[4][2];
  float bs1[2], bs2[2];
  for (int n = 0; n < 2; ++n) {
    const int col = wv * 32 + n * 16 + l15;
    bs1[n] = bias1g[col];
    bs2[n] = bias2g[col];
    for (int ks = 0; ks < 8; ++ks) {
      const int k0 = ks * 32 + lq * 8;
      s16x8 v;
#pragma unroll
      for (int j = 0; j < 8; ++j) v[j] = (short)w1b[(k0 + j) * 128 + col];
      b1f[ks][n] = __builtin_bit_cast(bf16x8, v);
    }
    for (int ks = 0; ks < 4; ++ks) {
      const int k0 = ks * 32 + lq * 8;
      s16x8 v;
#pragma unroll
      for (int j = 0; j < 8; ++j) v[j] = (short)w2b[(k0 + j) * 128 + col];
      b2f[ks][n] = __builtin_bit_cast(bf16x8, v);
    }
  }

  const int r = t >> 2;
  const int p = t & 3;
  const int rs = r & 7;

  for (int tile = blockIdx.x; tile < NE / 64; tile += EDGE_GRID) {
    __syncthreads();
    const int e0 = tile * 64;

    const int src = ei[e0 + r];
    if (p == 0) {
      const int d = ei[NE + e0 + r];
      sDst[r] = d;
      atomicAdd(&deg[d], 1.0f);
    }
    {  // node gather (f32 -> bf16): chunks 0..15
      const f32x4* nsv = (const f32x4*)(node_state + (size_t)src * 128 + p * 32);
#pragma unroll
      for (int j = 0; j < 4; ++j) {
        f32x4 x0 = nsv[2 * j], x1 = nsv[2 * j + 1];
        unsigned short buf[8];
#pragma unroll
        for (int i = 0; i < 4; ++i) { buf[i] = f2bf(x0[i]); buf[4 + i] = f2bf(x1[i]); }
        const int c = p * 4 + j;
        *(u32x4*)((char*)sX + r * 512 + ((c ^ rs) * 16)) = *(u32x4*)buf;
      }
    }
    {  // edge_state: f32 -> bf16, chunks 16..23
      const f32x4* es = (const f32x4*)(edge_state + (size_t)e0 * 64 + r * 64 + p * 16);
      f32x4 e0v = es[0], e1v = es[1], e2v = es[2], e3v = es[3];
      unsigned short bufa[8], bufb[8];
#pragma unroll
      for (int i = 0; i < 4; ++i) {
        bufa[i] = f2bf(e0v[i]); bufa[4 + i] = f2bf(e1v[i]);
        bufb[i] = f2bf(e2v[i]); bufb[4 + i] = f2bf(e3v[i]);
      }
      const int c = 16 + 2 * p;
      *(u32x4*)((char*)sX + r * 512 + ((c ^ rs) * 16)) = *(u32x4*)bufa;
      *(u32x4*)((char*)sX + r * 512 + (((c + 1) ^ rs) * 16)) = *(u32x4*)bufb;
    }
    {  // global (pre-converted bf16): chunks 24..31
      const u32x4* g = (const u32x4*)(gb + p * 16);
      const int c = 24 + 2 * p;
      *(u32x4*)((char*)sX + r * 512 + ((c ^ rs) * 16)) = g[0];
      *(u32x4*)((char*)sX + r * 512 + (((c + 1) ^ rs) * 16)) = g[1];
    }
    __syncthreads();

    // phase 1
    f32x4 acc[4][2];
#pragma unroll
    for (int m = 0; m < 4; ++m)
#pragma unroll
      for (int n = 0; n < 2; ++n)
        acc[m][n] = (f32x4){bs1[n], bs1[n], bs1[n], bs1[n]};
#pragma unroll
    for (int ks = 0; ks < 8; ++ks) {
      bf16x8 a[4];
#pragma unroll
      for (int m = 0; m < 4; ++m) {
        const int row = m * 16 + l15;
        a[m] = *(const bf16x8*)((const char*)sX + row * 512 + (((4 * ks + lq) ^ (row & 7)) * 16));
      }
#pragma unroll
      for (int m = 0; m < 4; ++m)
#pragma unroll
        for (int n = 0; n < 2; ++n)
          acc[m][n] = mfma16(a[m], b1f[ks][n], acc[m][n]);
    }
#pragma unroll
    for (int m = 0; m < 4; ++m)
#pragma unroll
      for (int n = 0; n < 2; ++n)
#pragma unroll
        for (int i = 0; i < 4; ++i) {
          const int row = m * 16 + lq * 4 + i;
          const int col = wv * 32 + n * 16 + l15;
          float v = acc[m][n][i];
          v = v > 0.f ? v : 0.f;
          *(unsigned short*)((char*)sH + row * 256 +
                             ((((col >> 3) ^ (row & 7)) * 16) + (col & 7) * 2)) = f2bf(v);
        }
    __syncthreads();

    // phase 2 + scatter
    f32x4 acc2[4][2];
#pragma unroll
    for (int m = 0; m < 4; ++m)
#pragma unroll
      for (int n = 0; n < 2; ++n)
        acc2[m][n] = (f32x4){bs2[n], bs2[n], bs2[n], bs2[n]};
#pragma unroll
    for (int ks = 0; ks < 4; ++ks) {
      bf16x8 a[4];
#pragma unroll
      for (int m = 0; m < 4; ++m) {
        const int row = m * 16 + l15;
        a[m] = *(const bf16x8*)((const char*)sH + row * 256 + (((4 * ks + lq) ^ (row & 7)) * 16));
      }
#pragma unroll
      for (int m = 0; m < 4; ++m)
#pragma unroll
        for (int n = 0; n < 2; ++n)
          acc2[m][n] = mfma16(a[m], b2f[ks][n], acc2[m][n]);
    }
#pragma unroll
    for (int m = 0; m < 4; ++m)
#pragma unroll
      for (int i = 0; i < 4; ++i) {
        const int row = m * 16 + lq * 4 + i;
        const int d = sDst[row];
#pragma unroll
        for (int n = 0; n < 2; ++n) {
          const int col = wv * 32 + n * 16 + l15;
          atomicAdd(&agg[(size_t)d * 128 + col], acc2[m][n][i]);
        }
      }
  }
}

// ---------------------------------------------------------------------------
// updB (r11-proven): h1 = relu(hpart + (agg/deg) @ U1[128:256])
// ---------------------------------------------------------------------------
__global__ __launch_bounds__(128, 3) void updB_kernel(
    const float* __restrict__ hpart,
    const float* __restrict__ agg,
    const float* __restrict__ deg,
    const float* __restrict__ u1,
    float* __restrict__ h1out)
{
  const int n = blockIdx.x * 128 + threadIdx.x;
  const bool act = n < NN;
  const size_t row = (size_t)(act ? n : 0) * 128;

  f32x4 acc[32];
#pragma unroll
  for (int c = 0; c < 32; ++c) acc[c] = *(const f32x4*)(hpart + row + 4 * c);

  const float rdeg = act ? (1.0f / fmaxf(deg[n], 1.0f)) : 0.0f;

  for (int k4 = 0; k4 < 32; ++k4) {
    const f32x4 x = *(const f32x4*)(agg + row + 4 * k4);
#pragma unroll
    for (int kk = 0; kk < 4; ++kk) {
      const float xk = x[kk] * rdeg;
      const float* wr = u1 + (size_t)(128 + 4 * k4 + kk) * 128;
#pragma unroll
      for (int c = 0; c < 32; ++c) acc[c] += xk * *(const f32x4*)(wr + 4 * c);
    }
  }

  if (act) {
    float* o = h1out + (size_t)n * 128;
#pragma unroll
    for (int c = 0; c < 32; ++c) {
      f32x4 v = acc[c];
#pragma unroll
      for (int i = 0; i < 4; ++i) v[i] = v[i] > 0.f ? v[i] : 0.f;
      *(f32x4*)(o + 4 * c) = v;
    }
  }
}

// ---------------------------------------------------------------------------
// upd2 (r11-proven): delta = h1 @ U2 + b2; x = node + delta; out = LN(x)
// ---------------------------------------------------------------------------
__global__ __launch_bounds__(128, 3) void upd2_kernel(
    const float* __restrict__ node_state,
    const float* __restrict__ h1,
    const float* __restrict__ u2,
    const float* __restrict__ b2,
    const float* __restrict__ lng,
    const float* __restrict__ lnb,
    float* __restrict__ out)
{
  const int n = blockIdx.x * 128 + threadIdx.x;
  const bool act = n < NN;
  const size_t row = (size_t)(act ? n : 0) * 128;

  f32x4 acc[32];
#pragma unroll
  for (int c = 0; c < 32; ++c) acc[c] = *(const f32x4*)(b2 + 4 * c);

  for (int k4 = 0; k4 < 32; ++k4) {
    const f32x4 h = *(const f32x4*)(h1 + row + 4 * k4);
#pragma unroll
    for (int kk = 0; kk < 4; ++kk) {
      const float hk = h[kk];
      const float* wr = u2 + (size_t)(4 * k4 + kk) * 128;
#pragma unroll
      for (int c = 0; c < 32; ++c) acc[c] += hk * *(const f32x4*)(wr + 4 * c);
    }
  }

  if (act) {
    float s = 0.f, s2 = 0.f;
#pragma unroll
    for (int c = 0; c < 32; ++c) {
      const f32x4 nd = *(const f32x4*)(node_state + row + 4 * c);
      f32x4 x = nd + acc[c];
      acc[c] = x;
#pragma unroll
      for (int i = 0; i < 4; ++i) { s += x[i]; s2 += x[i] * x[i]; }
    }
    const float mu = s * (1.0f / 128.0f);
    float var = s2 * (1.0f / 128.0f) - mu * mu;
    var = var < 0.f ? 0.f : var;
    const float rstd = rsqrtf(var + 1e-5f);
    float* o = out + (size_t)n * 128;
#pragma unroll
    for (int c = 0; c < 32; ++c) {
      const f32x4 g = *(const f32x4*)(lng + 4 * c);
      const f32x4 b = *(const f32x4*)(lnb + 4 * c);
      f32x4 x = acc[c];
#pragma unroll
      for (int i = 0; i < 4; ++i) x[i] = (x[i] - mu) * rstd * g[i] + b[i];
      *(f32x4*)(o + 4 * c) = x;
    }
  }
}

// ---------------------------------------------------------------------------
extern "C" void kernel_launch(void* const* d_in, const int* in_sizes, int n_in,
                              void* d_out, int out_size, void* d_ws, size_t ws_size,
                              hipStream_t stream)
{
  const float* node_state = (const float*)d_in[0];
  const int* ei           = (const int*)d_in[1];   // int64 in reference -> int32 from harness
  const float* edge_state = (const float*)d_in[2];
  const float* gstate     = (const float*)d_in[3];
  const float* msg_w1     = (const float*)d_in[4];
  const float* msg_b1     = (const float*)d_in[5];
  const float* msg_w2     = (const float*)d_in[6];
  const float* msg_b2     = (const float*)d_in[7];
  const float* upd_w1     = (const float*)d_in[8];
  const float* upd_b1     = (const float*)d_in[9];
  const float* upd_w2     = (const float*)d_in[10];
  const float* upd_b2     = (const float*)d_in[11];
  const float* ln_g       = (const float*)d_in[12];
  const float* ln_b       = (const float*)d_in[13];

  char* ws = (char*)d_ws;
  float* agg              = (float*)(ws + 0);                  //  51,200,000
  float* deg              = (float*)(ws + 51200000);           //     400,000
  float* hpart            = (float*)(ws + 51600000);           //  51,200,000
  float* h1buf            = (float*)(ws + 102800000);          //  51,200,000
  unsigned short* w1b     = (unsigned short*)(ws + 154000000); //      65,536
  unsigned short* w2b     = (unsigned short*)(ws + 154065536); //      32,768
  unsigned short* gb      = (unsigned short*)(ws + 154098304); //         128
  (void)ws_size; (void)in_sizes; (void)n_in; (void)out_size;

  hipMemsetAsync(ws, 0, 51600000, stream);  // agg + deg
  hipLaunchKernelGGL(convert_kernel, dim3(160), dim3(256), 0, stream,
                     msg_w1, msg_w2, gstate, w1b, w2b, gb);
  hipLaunchKernelGGL(fused_kernel, dim3(EDGE_GRID + UPDA_BLOCKS), dim3(256), 0, stream,
                     ei, edge_state, node_state, w1b, w2b, msg_b1, msg_b2, gb,
                     agg, deg, upd_w1, upd_b1, gstate, hpart);
  hipLaunchKernelGGL(updB_kernel, dim3((NN + 127) / 128), dim3(128), 0, stream,
                     hpart, agg, deg, upd_w1, h1buf);
  hipLaunchKernelGGL(upd2_kernel, dim3((NN + 127) / 128), dim3(128), 0, stream,
                     node_state, h1buf, upd_w2, upd_b2, ln_g, ln_b, (float*)d_out);
}